// Round 3
// baseline (886.136 us; speedup 1.0000x reference)
//
#include <hip/hip_runtime.h>
#include <cstddef>
#include <cstdint>

#define N_NODES 12288
#define D_IN    512
#define D_EMB   128
#define D_OUT   64
#define NEDGE   393216
#define CAP     160     // padded-CSR capacity per node (max degree ~65 for Poisson(32))

typedef __attribute__((ext_vector_type(8))) short short8;
typedef __attribute__((ext_vector_type(4))) float f32x4;

__device__ __forceinline__ ushort f2bf(float f) {
  uint32_t u = __float_as_uint(f);
  u += 0x7fffu + ((u >> 16) & 1u);
  return (ushort)(u >> 16);
}
__device__ __forceinline__ float bf2f(ushort h) {
  return __uint_as_float((uint32_t)h << 16);
}

// fp32x8 -> bf16 hi/lo fragments in registers
__device__ __forceinline__ void cvt8(const float* __restrict__ p,
                                     short8& h, short8& l)
{
  float4 a = *(const float4*)p;
  float4 b = *(const float4*)(p + 4);
  const float* f0 = &a.x;
  const float* f1 = &b.x;
#pragma unroll
  for (int q = 0; q < 4; ++q) {
    ushort h0 = f2bf(f0[q]);
    h[q] = (short)h0;     l[q] = (short)f2bf(f0[q] - bf2f(h0));
    ushort h1 = f2bf(f1[q]);
    h[q + 4] = (short)h1; l[q + 4] = (short)f2bf(f1[q] - bf2f(h1));
  }
}

// ---------------------------------------------------------------------------
// Single-wave 64x64 NT MFMA tile (3-term bf16 hi/lo), fp32 out. Used by out_x.
// Layouts (m89/m91, validated): A/B frag [m=lane&15][k=(lane>>4)*8+j],
// C/D: col=lane&15, row=(lane>>4)*4+reg.
// ---------------------------------------------------------------------------
__device__ __forceinline__ void mfma_tile64_f32out(
    int lane, int i0, int j0,
    const ushort* __restrict__ Ahi, const ushort* __restrict__ Alo,
    const ushort* __restrict__ Bhi, const ushort* __restrict__ Blo,
    float* __restrict__ Cf, int lda, int ldb, int K, int ldc)
{
  int lm = lane & 15, lk = lane >> 4;
  f32x4 acc[4][4];
#pragma unroll
  for (int r = 0; r < 4; ++r)
#pragma unroll
    for (int c = 0; c < 4; ++c) acc[r][c] = (f32x4){0.f, 0.f, 0.f, 0.f};

#pragma unroll 1
  for (int k0 = 0; k0 < K; k0 += 32) {
    int kk = k0 + lk * 8;
    short8 Ah[4], Al[4], Bh[4], Bl[4];
#pragma unroll
    for (int t = 0; t < 4; ++t) {
      size_t ra = (size_t)(i0 + t * 16 + lm) * lda + kk;
      size_t rb = (size_t)(j0 + t * 16 + lm) * ldb + kk;
      Ah[t] = *(const short8*)(Ahi + ra);
      Al[t] = *(const short8*)(Alo + ra);
      Bh[t] = *(const short8*)(Bhi + rb);
      Bl[t] = *(const short8*)(Blo + rb);
    }
#pragma unroll
    for (int r = 0; r < 4; ++r)
#pragma unroll
      for (int c = 0; c < 4; ++c) {
        acc[r][c] = __builtin_amdgcn_mfma_f32_16x16x32_bf16(Ah[r], Bh[c], acc[r][c], 0, 0, 0);
        acc[r][c] = __builtin_amdgcn_mfma_f32_16x16x32_bf16(Ah[r], Bl[c], acc[r][c], 0, 0, 0);
        acc[r][c] = __builtin_amdgcn_mfma_f32_16x16x32_bf16(Al[r], Bh[c], acc[r][c], 0, 0, 0);
      }
  }
#pragma unroll
  for (int r = 0; r < 4; ++r)
#pragma unroll
    for (int c = 0; c < 4; ++c) {
      int col = j0 + c * 16 + lm;
#pragma unroll
      for (int q = 0; q < 4; ++q) {
        int row = i0 + r * 16 + lk * 4 + q;
        Cf[(size_t)row * ldc + col] = acc[r][c][q];
      }
    }
}

// wave-inline int64/int32 detection
__device__ __forceinline__ bool edge_is64(const int* __restrict__ ei) {
  int hv = ei[2 * (threadIdx.x & 63) + 1];
  return __ballot(hv == 0) == 0xFFFFFFFFFFFFFFFFull;
}

// ---------------------------------------------------------------------------
// L1: fused x1+g+scores GEMM [0,96) | xt_splitk [96,608) | scatter [608,2144)
// All three roles mutually independent (deg pre-zeroed by memset).
// ---------------------------------------------------------------------------
__global__ __launch_bounds__(256) void mega1(
    const float* __restrict__ x,
    const float* __restrict__ Ws1, const float* __restrict__ b_s1,
    const float* __restrict__ Wg,
    const float* __restrict__ a_src, const float* __restrict__ a_dst,
    float* __restrict__ g, float* __restrict__ sc_s, float* __restrict__ sc_d,
    const float* __restrict__ Wa1, float* __restrict__ part,
    const int* __restrict__ ei, int* __restrict__ deg, int* __restrict__ csr)
{
  __shared__ float smem[16384];   // 64 KB union: x1 tile (GEMM) / Xs+Ws (splitk)
  int b = blockIdx.x;
  int tid = threadIdx.x;
  if (b < 96) {
    // ---- fused: x1 = relu(x@Ws1^T+b) -> LDS ; g = x1@Wg^T ; scores
    ushort* x1s = (ushort*)smem;  // [2][128*128] hi/lo, XOR-swizzled rows
    int lane = tid & 63, wv = tid >> 6;
    int lm = lane & 15, lk = lane >> 4;
    int wr = wv >> 1, wc = wv & 1;
    int i0 = b * 128;
    // phase A: x1 quadrant, K=512; both A (x) and B (Ws1) converted on the fly
    {
      f32x4 acc[4][4];
#pragma unroll
      for (int r = 0; r < 4; ++r)
#pragma unroll
        for (int c = 0; c < 4; ++c) acc[r][c] = (f32x4){0.f, 0.f, 0.f, 0.f};
#pragma unroll 1
      for (int k0 = 0; k0 < D_IN; k0 += 32) {
        int kk = k0 + lk * 8;
        short8 Ah[4], Al[4], Bh[4], Bl[4];
#pragma unroll
        for (int t = 0; t < 4; ++t) {
          cvt8(x + (size_t)(i0 + wr * 64 + t * 16 + lm) * D_IN + kk, Ah[t], Al[t]);
          cvt8(Ws1 + (size_t)(wc * 64 + t * 16 + lm) * D_IN + kk, Bh[t], Bl[t]);
        }
#pragma unroll
        for (int r = 0; r < 4; ++r)
#pragma unroll
          for (int c = 0; c < 4; ++c) {
            acc[r][c] = __builtin_amdgcn_mfma_f32_16x16x32_bf16(Ah[r], Bh[c], acc[r][c], 0, 0, 0);
            acc[r][c] = __builtin_amdgcn_mfma_f32_16x16x32_bf16(Ah[r], Bl[c], acc[r][c], 0, 0, 0);
            acc[r][c] = __builtin_amdgcn_mfma_f32_16x16x32_bf16(Al[r], Bh[c], acc[r][c], 0, 0, 0);
          }
      }
      // epilogue: bias + relu + bf16 split -> swizzled LDS
#pragma unroll
      for (int r = 0; r < 4; ++r)
#pragma unroll
        for (int c = 0; c < 4; ++c) {
          int col = wc * 64 + c * 16 + lm;
          float bv = b_s1[col];
#pragma unroll
          for (int q = 0; q < 4; ++q) {
            int row = wr * 64 + r * 16 + lk * 4 + q;
            float v = acc[r][c][q] + bv;
            v = fmaxf(v, 0.f);
            ushort hb = f2bf(v);
            int idx = ((row << 7) + col) ^ ((row & 7) << 3);
            x1s[idx] = hb;
            x1s[16384 + idx] = f2bf(v - bf2f(hb));
          }
        }
    }
    __syncthreads();
    // phase B (waves 0,1): g = x1 @ Wg^T (K=128, Wg converted on the fly) + scores
    if (wv < 2) {
      f32x4 acc[4][4];
#pragma unroll
      for (int r = 0; r < 4; ++r)
#pragma unroll
        for (int c = 0; c < 4; ++c) acc[r][c] = (f32x4){0.f, 0.f, 0.f, 0.f};
#pragma unroll 1
      for (int k0 = 0; k0 < D_EMB; k0 += 32) {
        int kk = k0 + lk * 8;
        short8 Ah[4], Al[4], Bh[4], Bl[4];
#pragma unroll
        for (int t = 0; t < 4; ++t) {
          int arow = wv * 64 + t * 16 + lm;
          int aidx = ((arow << 7) + kk) ^ ((arow & 7) << 3);
          Ah[t] = *(const short8*)&x1s[aidx];
          Al[t] = *(const short8*)&x1s[16384 + aidx];
          cvt8(Wg + (size_t)(t * 16 + lm) * D_EMB + kk, Bh[t], Bl[t]);
        }
#pragma unroll
        for (int r = 0; r < 4; ++r)
#pragma unroll
          for (int c = 0; c < 4; ++c) {
            acc[r][c] = __builtin_amdgcn_mfma_f32_16x16x32_bf16(Ah[r], Bh[c], acc[r][c], 0, 0, 0);
            acc[r][c] = __builtin_amdgcn_mfma_f32_16x16x32_bf16(Ah[r], Bl[c], acc[r][c], 0, 0, 0);
            acc[r][c] = __builtin_amdgcn_mfma_f32_16x16x32_bf16(Al[r], Bh[c], acc[r][c], 0, 0, 0);
          }
      }
      // write g (fp32) + fused attention scores
#pragma unroll
      for (int r = 0; r < 4; ++r)
#pragma unroll
        for (int c = 0; c < 4; ++c) {
          int col = c * 16 + lm;
#pragma unroll
          for (int q = 0; q < 4; ++q) {
            int row = i0 + wv * 64 + r * 16 + lk * 4 + q;
            g[(size_t)row * D_OUT + col] = acc[r][c][q];
          }
        }
      float asv[4], adv[4];
#pragma unroll
      for (int c = 0; c < 4; ++c) {
        asv[c] = a_src[c * 16 + lm];
        adv[c] = a_dst[c * 16 + lm];
      }
#pragma unroll
      for (int r = 0; r < 4; ++r)
#pragma unroll
        for (int q = 0; q < 4; ++q) {
          float s = 0.f, d = 0.f;
#pragma unroll
          for (int c = 0; c < 4; ++c) {
            float v = acc[r][c][q];
            s = fmaf(v, asv[c], s);
            d = fmaf(v, adv[c], d);
          }
#pragma unroll
          for (int off = 1; off < 16; off <<= 1) {
            s += __shfl_xor(s, off);
            d += __shfl_xor(d, off);
          }
          if (lm == 0) {
            int row = i0 + wv * 64 + r * 16 + lk * 4 + q;
            sc_s[row] = s;
            sc_d[row] = d;
          }
        }
    }
  } else if (b < 608) {
    // ---- xt pre-activation partials over 192-row chunks (no atomics)
    float* Xs = smem;           // [32][64]
    float* Ws = smem + 2048;    // [32][128]
    int sb = b - 96;
    int c0 = (sb & 7) * 64;
    int i0 = (sb >> 3) * 192;
    float* pout = part + (size_t)(sb >> 3) * (D_IN * D_EMB);
    int txc = tid & 15, txj = tid >> 4;
    float acc[4][8] = {};
    for (int ib = 0; ib < 192; ib += 32) {
#pragma unroll
      for (int p = 0; p < 2; ++p) {
        int idx = tid + p * 256;
        int row = idx >> 4, q = idx & 15;
        *(float4*)&Xs[row * 64 + q * 4] =
            *(const float4*)(x + (size_t)(i0 + ib + row) * D_IN + c0 + q * 4);
      }
#pragma unroll
      for (int p = 0; p < 4; ++p) {
        int idx = tid + p * 256;
        int j = idx >> 3, q = idx & 7;
        float4 v = *(const float4*)(Wa1 + (size_t)j * N_NODES + i0 + ib + q * 4);
        Ws[(q * 4 + 0) * 128 + j] = v.x; Ws[(q * 4 + 1) * 128 + j] = v.y;
        Ws[(q * 4 + 2) * 128 + j] = v.z; Ws[(q * 4 + 3) * 128 + j] = v.w;
      }
      __syncthreads();
#pragma unroll
      for (int ii = 0; ii < 32; ++ii) {
        float a[4], bb[8];
        *(float4*)a = *(const float4*)&Xs[ii * 64 + txc * 4];
        *(float4*)&bb[0] = *(const float4*)&Ws[ii * 128 + txj * 8];
        *(float4*)&bb[4] = *(const float4*)&Ws[ii * 128 + txj * 8 + 4];
#pragma unroll
        for (int r = 0; r < 4; ++r)
#pragma unroll
          for (int c = 0; c < 8; ++c)
            acc[r][c] = fmaf(a[r], bb[c], acc[r][c]);
      }
      __syncthreads();
    }
#pragma unroll
    for (int r = 0; r < 4; ++r) {
      float4 o0, o1;
      o0.x = acc[r][0]; o0.y = acc[r][1]; o0.z = acc[r][2]; o0.w = acc[r][3];
      o1.x = acc[r][4]; o1.y = acc[r][5]; o1.z = acc[r][6]; o1.w = acc[r][7];
      size_t off = (size_t)(c0 + txc * 4 + r) * D_EMB + txj * 8;
      *(float4*)&pout[off] = o0;
      *(float4*)&pout[off + 4] = o1;
    }
  } else {
    // ---- single-pass padded-CSR scatter
    bool is64 = edge_is64(ei);
    int e = (b - 608) * 256 + tid;
    int src = is64 ? ei[2 * e] : ei[e];
    int dst = is64 ? ei[2 * (NEDGE + e)] : ei[NEDGE + e];
    int p = atomicAdd(&deg[dst], 1);
    csr[(size_t)dst * CAP + p] = src;
  }
}

// ---------------------------------------------------------------------------
// L2: GAT aggregation [0,3072) | xa (part-reduce + GEMM -> bf16) [3072,3080)
// ---------------------------------------------------------------------------
#define WCAP 192
__global__ __launch_bounds__(256) void mega2(
    const int* __restrict__ deg, const int* __restrict__ csr,
    const float* __restrict__ sc_s, const float* __restrict__ sc_d,
    const float* __restrict__ g, const float* __restrict__ b_g,
    ushort* __restrict__ hhi, ushort* __restrict__ hlo,
    const float* __restrict__ part, const float* __restrict__ b_a1,
    const float* __restrict__ Wa2, const float* __restrict__ b_a2,
    ushort* __restrict__ xahi, ushort* __restrict__ xalo)
{
  __shared__ float smem[10240];   // 40 KB union: GAT wbuf/sbuf | xa As_T+Bs
  int b = blockIdx.x;
  int tid = threadIdx.x;
  if (b < 3072) {
    float (*wbuf)[WCAP] = (float(*)[WCAP])smem;
    int   (*sbuf)[WCAP] = (int(*)[WCAP])(smem + 4 * WCAP);
    int lane = tid & 63;
    int w = tid >> 6;
    int i = b * 4 + w;
    int dg = deg[i];
    int base = i * CAP;
    float scd = sc_d[i];
    float mymax = -3.4e38f;
    for (int j = lane; j <= dg; j += 64) {
      int s = (j < dg) ? csr[base + j] : i;
      float e = sc_s[s] + scd;
      e = (e > 0.f) ? e : 0.2f * e;
      mymax = fmaxf(mymax, e);
      if (j < WCAP) sbuf[w][j] = s;
    }
#pragma unroll
    for (int off = 32; off; off >>= 1) mymax = fmaxf(mymax, __shfl_xor(mymax, off));
    float sum = 0.f;
    for (int j = lane; j <= dg; j += 64) {
      int s = (j < WCAP) ? sbuf[w][j] : ((j < dg) ? csr[base + j] : i);
      float e = sc_s[s] + scd;
      e = (e > 0.f) ? e : 0.2f * e;
      float ex = __expf(e - mymax);
      sum += ex;
      if (j < WCAP) wbuf[w][j] = ex;
    }
#pragma unroll
    for (int off = 32; off; off >>= 1) sum += __shfl_xor(sum, off);
    float inv = 1.f / sum;
    float acc = 0.f;   // lane == feature
    for (int j = 0; j <= dg; ++j) {
      int s; float ex;
      if (j < WCAP) { s = sbuf[w][j]; ex = wbuf[w][j]; }
      else {
        s = (j < dg) ? csr[base + j] : i;
        float e = sc_s[s] + scd;
        e = (e > 0.f) ? e : 0.2f * e;
        ex = __expf(e - mymax);
      }
      acc = fmaf(ex * inv, g[(size_t)s * 64 + lane], acc);
    }
    float val = acc + b_g[lane];
    size_t o = (size_t)i * 64 + lane;
    ushort hi = f2bf(val);
    hhi[o] = hi;
    hlo[o] = f2bf(val - bf2f(hi));
  } else {
    // ---- xa = relu(sum_chunks(part) + b_a1) @ W_a2^T + b_a2 -> bf16 hi/lo
    float* AsT = smem;          // [128][64]  (k-major xt tile, post-relu)
    float* Bs  = smem + 8192;   // [32][64]
    int m0 = (b - 3072) * 64;
    // reduce 64 chunks: thread owns row (tid>>2), cols [(tid&3)*32, +32)
    {
      int lr = tid >> 2;
      int j0 = (tid & 3) * 32;
      f32x4 acc8[8];
#pragma unroll
      for (int q = 0; q < 8; ++q) acc8[q] = (f32x4){0.f, 0.f, 0.f, 0.f};
      const float* src = part + (size_t)(m0 + lr) * D_EMB + j0;
#pragma unroll 4
      for (int ch = 0; ch < 64; ++ch) {
        const float* p = src + (size_t)ch * (D_IN * D_EMB);
#pragma unroll
        for (int q = 0; q < 8; ++q) {
          float4 v = *(const float4*)(p + q * 4);
          acc8[q].x += v.x; acc8[q].y += v.y; acc8[q].z += v.z; acc8[q].w += v.w;
        }
      }
#pragma unroll
      for (int q = 0; q < 8; ++q) {
        const float* pv = (const float*)&acc8[q];
#pragma unroll
        for (int e = 0; e < 4; ++e) {
          int j = j0 + q * 4 + e;
          float v = pv[e] + b_a1[j];
          AsT[j * 64 + lr] = fmaxf(v, 0.f);
        }
      }
    }
    __syncthreads();
    int tx = tid & 15, ty = tid >> 4;
    float acc[4][4] = {};
    for (int k0 = 0; k0 < D_EMB; k0 += 32) {
#pragma unroll
      for (int p = 0; p < 2; ++p) {
        int idx = tid + p * 256;
        int row = idx >> 3;
        int kq = idx & 7;
        float4 vb = *(const float4*)(Wa2 + (size_t)row * D_EMB + k0 + kq * 4);
        Bs[(kq * 4 + 0) * 64 + row] = vb.x; Bs[(kq * 4 + 1) * 64 + row] = vb.y;
        Bs[(kq * 4 + 2) * 64 + row] = vb.z; Bs[(kq * 4 + 3) * 64 + row] = vb.w;
      }
      __syncthreads();
#pragma unroll
      for (int k = 0; k < 32; ++k) {
        float a[4], bb[4];
        *(float4*)a = *(const float4*)&AsT[(k0 + k) * 64 + ty * 4];
        *(float4*)bb = *(const float4*)&Bs[k * 64 + tx * 4];
#pragma unroll
        for (int r = 0; r < 4; ++r)
#pragma unroll
          for (int c = 0; c < 4; ++c)
            acc[r][c] = fmaf(a[r], bb[c], acc[r][c]);
      }
      __syncthreads();
    }
#pragma unroll
    for (int r = 0; r < 4; ++r) {
      int m = m0 + ty * 4 + r;
      ushort4 h, l;
      ushort* ph = &h.x; ushort* pl = &l.x;
#pragma unroll
      for (int c = 0; c < 4; ++c) {
        float v = acc[r][c] + b_a2[tx * 4 + c];
        ushort hb = f2bf(v);
        ph[c] = hb;
        pl[c] = f2bf(v - bf2f(hb));
      }
      *(ushort4*)(xahi + (size_t)m * D_OUT + tx * 4) = h;
      *(ushort4*)(xalo + (size_t)m * D_OUT + tx * 4) = l;
    }
  }
}

// ---------------------------------------------------------------------------
// L3: out_x [0,384) | sigmoid(h h^T) [384,9600)
// ---------------------------------------------------------------------------
__global__ __launch_bounds__(256) void mega3(
    const ushort* __restrict__ hhi, const ushort* __restrict__ hlo,
    const ushort* __restrict__ xahi, const ushort* __restrict__ xalo,
    float* __restrict__ out_x, float* __restrict__ out_s)
{
  int b = blockIdx.x;
  int lane = threadIdx.x & 63;
  int wv = threadIdx.x >> 6;
  if (b < 384) {
    int i0 = (b >> 2) * 128 + (wv >> 1) * 64;
    int j0 = (b & 3) * 128 + (wv & 1) * 64;
    mfma_tile64_f32out(lane, i0, j0, hhi, hlo, xahi, xalo,
                       out_x, D_OUT, D_OUT, D_OUT, D_IN);
    return;
  }
  int bb = b - 384;
  int iT = bb / 96;
  int jT = bb - iT * 96;
  int i0 = iT * 128 + (wv >> 1) * 64;
  int j0 = jT * 128 + (wv & 1) * 64;
  int lm = lane & 15, lk = lane >> 4;
  f32x4 acc[4][4];
#pragma unroll
  for (int r = 0; r < 4; ++r)
#pragma unroll
    for (int c = 0; c < 4; ++c) acc[r][c] = (f32x4){0.f, 0.f, 0.f, 0.f};
#pragma unroll
  for (int ks = 0; ks < 2; ++ks) {
    short8 Ah[4], Al[4], Bh[4], Bl[4];
#pragma unroll
    for (int t = 0; t < 4; ++t) {
      size_t ra = (size_t)(i0 + t * 16 + lm) * 64 + ks * 32 + lk * 8;
      size_t rb = (size_t)(j0 + t * 16 + lm) * 64 + ks * 32 + lk * 8;
      Ah[t] = *(const short8*)(hhi + ra);
      Al[t] = *(const short8*)(hlo + ra);
      Bh[t] = *(const short8*)(hhi + rb);
      Bl[t] = *(const short8*)(hlo + rb);
    }
#pragma unroll
    for (int r = 0; r < 4; ++r)
#pragma unroll
      for (int c = 0; c < 4; ++c) {
        acc[r][c] = __builtin_amdgcn_mfma_f32_16x16x32_bf16(Ah[r], Bh[c], acc[r][c], 0, 0, 0);
        acc[r][c] = __builtin_amdgcn_mfma_f32_16x16x32_bf16(Ah[r], Bl[c], acc[r][c], 0, 0, 0);
        acc[r][c] = __builtin_amdgcn_mfma_f32_16x16x32_bf16(Al[r], Bh[c], acc[r][c], 0, 0, 0);
      }
  }
#pragma unroll
  for (int r = 0; r < 4; ++r)
#pragma unroll
    for (int c = 0; c < 4; ++c) {
#pragma unroll
      for (int q = 0; q < 4; ++q) {
        float v = acc[r][c][q];
        float ex = __expf(-v);
#if __has_builtin(__builtin_amdgcn_rcpf)
        float s = __builtin_amdgcn_rcpf(1.f + ex);
#else
        float s = 1.f / (1.f + ex);
#endif
        out_s[(size_t)(i0 + r * 16 + lk * 4 + q) * N_NODES + (j0 + c * 16 + lm)] = s;
      }
    }
}

// ---------------------------------------------------------------------------
extern "C" void kernel_launch(void* const* d_in, const int* in_sizes, int n_in,
                              void* d_out, int out_size, void* d_ws, size_t ws_size,
                              hipStream_t stream)
{
  const float* x     = (const float*)d_in[0];
  const float* W_s1  = (const float*)d_in[1];
  const float* b_s1  = (const float*)d_in[2];
  const float* W_g   = (const float*)d_in[3];
  const float* a_src = (const float*)d_in[4];
  const float* a_dst = (const float*)d_in[5];
  const float* b_g   = (const float*)d_in[6];
  const float* W_a1  = (const float*)d_in[7];
  const float* b_a1  = (const float*)d_in[8];
  const float* W_a2  = (const float*)d_in[9];
  const float* b_a2  = (const float*)d_in[10];
  const int*   ei    = (const int*)d_in[11];

  // ---- workspace carve-up
  float* ws   = (float*)d_ws;
  float* g    = ws;                               // 786432
  float* sc_s = g + (size_t)N_NODES * D_OUT;      // 12288
  float* sc_d = sc_s + N_NODES;                   // 12288
  float* part = sc_d + N_NODES;                   // 64*65536 = 4194304
  int* deg    = (int*)(part + (size_t)64 * D_IN * D_EMB);  // 12288
  int* csr    = deg + N_NODES;                    // 12288*160 = 1966080
  ushort* up  = (ushort*)(csr + (size_t)N_NODES * CAP);
  ushort* hhi   = up;                        up += (size_t)N_NODES * D_OUT;
  ushort* hlo   = up;                        up += (size_t)N_NODES * D_OUT;
  ushort* xahi  = up;                        up += (size_t)D_IN * D_OUT;
  ushort* xalo  = up;                        up += (size_t)D_IN * D_OUT;
  (void)ws_size; (void)in_sizes; (void)n_in; (void)out_size;

  float* out_x = (float*)d_out;                       // 12288*512
  float* out_s = out_x + (size_t)N_NODES * D_IN;      // 12288*12288

  hipMemsetAsync(deg, 0, N_NODES * sizeof(int), stream);
  // L1: fused x1+g+scores || xt_splitk || scatter   (2144 blocks)
  mega1<<<2144, 256, 0, stream>>>(x, W_s1, b_s1, W_g, a_src, a_dst,
      g, sc_s, sc_d, W_a1, part, ei, deg, csr);
  // L2: GAT || xa (part-reduce + GEMM)              (3080 blocks)
  mega2<<<3080, 256, 0, stream>>>(deg, csr, sc_s, sc_d, g, b_g,
      hhi, hlo, part, b_a1, W_a2, b_a2, xahi, xalo);
  // L3: out_x || sigmoid(h h^T)                     (9600 blocks)
  mega3<<<9600, 256, 0, stream>>>(hhi, hlo, xahi, xalo, out_x, out_s);
}

// Round 4
// 792.313 us; speedup vs baseline: 1.1184x; 1.1184x over previous
//
#include <hip/hip_runtime.h>
#include <cstddef>
#include <cstdint>

#define N_NODES 12288
#define D_IN    512
#define D_EMB   128
#define D_OUT   64
#define NEDGE   393216
#define CAP     160     // padded-CSR capacity per node (max degree ~65 for Poisson(32))

typedef __attribute__((ext_vector_type(8))) short short8;
typedef __attribute__((ext_vector_type(4))) float f32x4;

__device__ __forceinline__ ushort f2bf(float f) {
  uint32_t u = __float_as_uint(f);
  u += 0x7fffu + ((u >> 16) & 1u);
  return (ushort)(u >> 16);
}
__device__ __forceinline__ float bf2f(ushort h) {
  return __uint_as_float((uint32_t)h << 16);
}

__device__ __forceinline__ void conv4(const float* __restrict__ src,
    ushort* __restrict__ hi, ushort* __restrict__ lo, int idx)
{
  float4 v = *(const float4*)(src + idx);
  const float* pv = &v.x;
  ushort4 h, l;
  ushort* ph = &h.x; ushort* pl = &l.x;
#pragma unroll
  for (int q = 0; q < 4; ++q) {
    ph[q] = f2bf(pv[q]);
    pl[q] = f2bf(pv[q] - bf2f(ph[q]));
  }
  *(ushort4*)(hi + idx) = h;
  *(ushort4*)(lo + idx) = l;
}

// fp32x8 -> bf16 hi/lo fragments in registers
__device__ __forceinline__ void cvt8(const float* __restrict__ p,
                                     short8& h, short8& l)
{
  float4 a = *(const float4*)p;
  float4 b = *(const float4*)(p + 4);
  const float* f0 = &a.x;
  const float* f1 = &b.x;
#pragma unroll
  for (int q = 0; q < 4; ++q) {
    ushort h0 = f2bf(f0[q]);
    h[q] = (short)h0;     l[q] = (short)f2bf(f0[q] - bf2f(h0));
    ushort h1 = f2bf(f1[q]);
    h[q + 4] = (short)h1; l[q + 4] = (short)f2bf(f1[q] - bf2f(h1));
  }
}

// ---------------------------------------------------------------------------
// Single-wave 64x64 NT MFMA tile (3-term bf16 hi/lo), fp32 out via NT stores.
// Layouts (m89/m91, validated): A/B frag [m=lane&15][k=(lane>>4)*8+j],
// C/D: col=lane&15, row=(lane>>4)*4+reg.
// ---------------------------------------------------------------------------
__device__ __forceinline__ void mfma_tile64_f32out(
    int lane, int i0, int j0,
    const ushort* __restrict__ Ahi, const ushort* __restrict__ Alo,
    const ushort* __restrict__ Bhi, const ushort* __restrict__ Blo,
    float* __restrict__ Cf, int lda, int ldb, int K, int ldc)
{
  int lm = lane & 15, lk = lane >> 4;
  f32x4 acc[4][4];
#pragma unroll
  for (int r = 0; r < 4; ++r)
#pragma unroll
    for (int c = 0; c < 4; ++c) acc[r][c] = (f32x4){0.f, 0.f, 0.f, 0.f};

#pragma unroll 1
  for (int k0 = 0; k0 < K; k0 += 32) {
    int kk = k0 + lk * 8;
    short8 Ah[4], Al[4], Bh[4], Bl[4];
#pragma unroll
    for (int t = 0; t < 4; ++t) {
      size_t ra = (size_t)(i0 + t * 16 + lm) * lda + kk;
      size_t rb = (size_t)(j0 + t * 16 + lm) * ldb + kk;
      Ah[t] = *(const short8*)(Ahi + ra);
      Al[t] = *(const short8*)(Alo + ra);
      Bh[t] = *(const short8*)(Bhi + rb);
      Bl[t] = *(const short8*)(Blo + rb);
    }
#pragma unroll
    for (int r = 0; r < 4; ++r)
#pragma unroll
      for (int c = 0; c < 4; ++c) {
        acc[r][c] = __builtin_amdgcn_mfma_f32_16x16x32_bf16(Ah[r], Bh[c], acc[r][c], 0, 0, 0);
        acc[r][c] = __builtin_amdgcn_mfma_f32_16x16x32_bf16(Ah[r], Bl[c], acc[r][c], 0, 0, 0);
        acc[r][c] = __builtin_amdgcn_mfma_f32_16x16x32_bf16(Al[r], Bh[c], acc[r][c], 0, 0, 0);
      }
  }
#pragma unroll
  for (int r = 0; r < 4; ++r)
#pragma unroll
    for (int c = 0; c < 4; ++c) {
      int col = j0 + c * 16 + lm;
#pragma unroll
      for (int q = 0; q < 4; ++q) {
        int row = i0 + r * 16 + lk * 4 + q;
        __builtin_nontemporal_store(acc[r][c][q], &Cf[(size_t)row * ldc + col]);
      }
    }
}

// ---------------------------------------------------------------------------
// L1: xt_splitk [0,512) | conv W [512,584) | zero deg [584,632)
// ---------------------------------------------------------------------------
__global__ __launch_bounds__(256) void prep_kernel(
    const float* __restrict__ x, const float* __restrict__ Ws1,
    const float* __restrict__ Wg, const float* __restrict__ Wa1,
    ushort* __restrict__ s1h, ushort* __restrict__ s1l,
    ushort* __restrict__ wgh, ushort* __restrict__ wgl,
    int* __restrict__ deg, float* __restrict__ part)
{
  __shared__ float smem[6144];   // Xs 32x64 | Ws 32x128
  int b = blockIdx.x;
  int tid = threadIdx.x;
  if (b < 512) {
    // xt pre-activation partials over 192-row chunks (no atomics)
    float* Xs = smem;           // [32][64]
    float* Ws = smem + 2048;    // [32][128]
    int c0 = (b & 7) * 64;
    int i0 = (b >> 3) * 192;
    float* pout = part + (size_t)(b >> 3) * (D_IN * D_EMB);
    int txc = tid & 15, txj = tid >> 4;
    float acc[4][8] = {};
    for (int ib = 0; ib < 192; ib += 32) {
#pragma unroll
      for (int p = 0; p < 2; ++p) {
        int idx = tid + p * 256;
        int row = idx >> 4, q = idx & 15;
        *(float4*)&Xs[row * 64 + q * 4] =
            *(const float4*)(x + (size_t)(i0 + ib + row) * D_IN + c0 + q * 4);
      }
#pragma unroll
      for (int p = 0; p < 4; ++p) {
        int idx = tid + p * 256;
        int j = idx >> 3, q = idx & 7;
        float4 v = *(const float4*)(Wa1 + (size_t)j * N_NODES + i0 + ib + q * 4);
        Ws[(q * 4 + 0) * 128 + j] = v.x; Ws[(q * 4 + 1) * 128 + j] = v.y;
        Ws[(q * 4 + 2) * 128 + j] = v.z; Ws[(q * 4 + 3) * 128 + j] = v.w;
      }
      __syncthreads();
#pragma unroll
      for (int ii = 0; ii < 32; ++ii) {
        float a[4], bb[8];
        *(float4*)a = *(const float4*)&Xs[ii * 64 + txc * 4];
        *(float4*)&bb[0] = *(const float4*)&Ws[ii * 128 + txj * 8];
        *(float4*)&bb[4] = *(const float4*)&Ws[ii * 128 + txj * 8 + 4];
#pragma unroll
        for (int r = 0; r < 4; ++r)
#pragma unroll
          for (int c = 0; c < 8; ++c)
            acc[r][c] = fmaf(a[r], bb[c], acc[r][c]);
      }
      __syncthreads();
    }
#pragma unroll
    for (int r = 0; r < 4; ++r) {
      float4 o0, o1;
      o0.x = acc[r][0]; o0.y = acc[r][1]; o0.z = acc[r][2]; o0.w = acc[r][3];
      o1.x = acc[r][4]; o1.y = acc[r][5]; o1.z = acc[r][6]; o1.w = acc[r][7];
      size_t off = (size_t)(c0 + txc * 4 + r) * D_EMB + txj * 8;
      *(float4*)&pout[off] = o0;
      *(float4*)&pout[off + 4] = o1;
    }
  } else if (b < 584) {
    int bb = b - 512;
    if (bb < 64) conv4(Ws1, s1h, s1l, (bb * 256 + tid) * 4);
    else         conv4(Wg,  wgh, wgl, ((bb - 64) * 256 + tid) * 4);
  } else {
    deg[(b - 584) * 256 + tid] = 0;
  }
}

// wave-inline int64/int32 detection
__device__ __forceinline__ bool edge_is64(const int* __restrict__ ei) {
  int hv = ei[2 * (threadIdx.x & 63) + 1];
  return __ballot(hv == 0) == 0xFFFFFFFFFFFFFFFFull;
}

// ---------------------------------------------------------------------------
// L2: fused x1+g+scores [0,96) | padded-CSR scatter [96,1632) | xt_ep [1632,1888)
// ---------------------------------------------------------------------------
__global__ __launch_bounds__(256) void l2_kernel(
    const int* __restrict__ ei, int* __restrict__ deg, int* __restrict__ csr,
    const float* __restrict__ x,
    const ushort* __restrict__ s1h, const ushort* __restrict__ s1l,
    const float* __restrict__ b_s1,
    const ushort* __restrict__ wgh, const ushort* __restrict__ wgl,
    float* __restrict__ g,
    const float* __restrict__ a_src, const float* __restrict__ a_dst,
    float* __restrict__ sc_s, float* __restrict__ sc_d,
    const float* __restrict__ part, const float* __restrict__ b_a1,
    float* __restrict__ xt)
{
  // 64 KB: x1 tile (128x128 bf16 hi + lo), XOR-swizzled rows
  __shared__ ushort x1s[2][128 * 128];
  int b = blockIdx.x;
  int tid = threadIdx.x;
  if (b < 96) {
    int lane = tid & 63, wv = tid >> 6;
    int lm = lane & 15, lk = lane >> 4;
    int wr = wv >> 1, wc = wv & 1;
    int i0 = b * 128;
    // ---- phase A: x1 quadrant = relu(x @ Ws1^T + b), K=512, fp32 A on the fly
    {
      f32x4 acc[4][4];
#pragma unroll
      for (int r = 0; r < 4; ++r)
#pragma unroll
        for (int c = 0; c < 4; ++c) acc[r][c] = (f32x4){0.f, 0.f, 0.f, 0.f};
#pragma unroll 1
      for (int k0 = 0; k0 < D_IN; k0 += 32) {
        int kk = k0 + lk * 8;
        short8 Ah[4], Al[4], Bh[4], Bl[4];
#pragma unroll
        for (int t = 0; t < 4; ++t) {
          const float* pa = x + (size_t)(i0 + wr * 64 + t * 16 + lm) * D_IN + kk;
          cvt8(pa, Ah[t], Al[t]);
          size_t rb = (size_t)(wc * 64 + t * 16 + lm) * D_IN + kk;
          Bh[t] = *(const short8*)(s1h + rb);
          Bl[t] = *(const short8*)(s1l + rb);
        }
#pragma unroll
        for (int r = 0; r < 4; ++r)
#pragma unroll
          for (int c = 0; c < 4; ++c) {
            acc[r][c] = __builtin_amdgcn_mfma_f32_16x16x32_bf16(Ah[r], Bh[c], acc[r][c], 0, 0, 0);
            acc[r][c] = __builtin_amdgcn_mfma_f32_16x16x32_bf16(Ah[r], Bl[c], acc[r][c], 0, 0, 0);
            acc[r][c] = __builtin_amdgcn_mfma_f32_16x16x32_bf16(Al[r], Bh[c], acc[r][c], 0, 0, 0);
          }
      }
      // epilogue: bias + relu + bf16 split -> swizzled LDS
#pragma unroll
      for (int r = 0; r < 4; ++r)
#pragma unroll
        for (int c = 0; c < 4; ++c) {
          int col = wc * 64 + c * 16 + lm;
          float bv = b_s1[col];
#pragma unroll
          for (int q = 0; q < 4; ++q) {
            int row = wr * 64 + r * 16 + lk * 4 + q;
            float v = acc[r][c][q] + bv;
            v = fmaxf(v, 0.f);
            ushort hb = f2bf(v);
            int idx = ((row << 7) + col) ^ ((row & 7) << 3);
            x1s[0][idx] = hb;
            x1s[1][idx] = f2bf(v - bf2f(hb));
          }
        }
    }
    __syncthreads();
    // ---- phase B (waves 0,1): g = x1 @ Wg^T (K=128) + fused scores
    if (wv < 2) {
      f32x4 acc[4][4];
#pragma unroll
      for (int r = 0; r < 4; ++r)
#pragma unroll
        for (int c = 0; c < 4; ++c) acc[r][c] = (f32x4){0.f, 0.f, 0.f, 0.f};
#pragma unroll 1
      for (int k0 = 0; k0 < D_EMB; k0 += 32) {
        int kk = k0 + lk * 8;
        short8 Ah[4], Al[4], Bh[4], Bl[4];
#pragma unroll
        for (int t = 0; t < 4; ++t) {
          int arow = wv * 64 + t * 16 + lm;
          int aidx = ((arow << 7) + kk) ^ ((arow & 7) << 3);
          Ah[t] = *(const short8*)&x1s[0][aidx];
          Al[t] = *(const short8*)&x1s[1][aidx];
          size_t rb = (size_t)(t * 16 + lm) * D_EMB + kk;
          Bh[t] = *(const short8*)(wgh + rb);
          Bl[t] = *(const short8*)(wgl + rb);
        }
#pragma unroll
        for (int r = 0; r < 4; ++r)
#pragma unroll
          for (int c = 0; c < 4; ++c) {
            acc[r][c] = __builtin_amdgcn_mfma_f32_16x16x32_bf16(Ah[r], Bh[c], acc[r][c], 0, 0, 0);
            acc[r][c] = __builtin_amdgcn_mfma_f32_16x16x32_bf16(Ah[r], Bl[c], acc[r][c], 0, 0, 0);
            acc[r][c] = __builtin_amdgcn_mfma_f32_16x16x32_bf16(Al[r], Bh[c], acc[r][c], 0, 0, 0);
          }
      }
      // write g (fp32) + fused attention scores
#pragma unroll
      for (int r = 0; r < 4; ++r)
#pragma unroll
        for (int c = 0; c < 4; ++c) {
          int col = c * 16 + lm;
#pragma unroll
          for (int q = 0; q < 4; ++q) {
            int row = i0 + wv * 64 + r * 16 + lk * 4 + q;
            g[(size_t)row * D_OUT + col] = acc[r][c][q];
          }
        }
      float asv[4], adv[4];
#pragma unroll
      for (int c = 0; c < 4; ++c) {
        asv[c] = a_src[c * 16 + lm];
        adv[c] = a_dst[c * 16 + lm];
      }
#pragma unroll
      for (int r = 0; r < 4; ++r)
#pragma unroll
        for (int q = 0; q < 4; ++q) {
          float s = 0.f, d = 0.f;
#pragma unroll
          for (int c = 0; c < 4; ++c) {
            float v = acc[r][c][q];
            s = fmaf(v, asv[c], s);
            d = fmaf(v, adv[c], d);
          }
#pragma unroll
          for (int off = 1; off < 16; off <<= 1) {
            s += __shfl_xor(s, off);
            d += __shfl_xor(d, off);
          }
          if (lm == 0) {
            int row = i0 + wv * 64 + r * 16 + lk * 4 + q;
            sc_s[row] = s;
            sc_d[row] = d;
          }
        }
    }
  } else if (b < 1632) {
    // single-pass padded-CSR scatter
    bool is64 = edge_is64(ei);
    int e = (b - 96) * 256 + tid;
    int src = is64 ? ei[2 * e] : ei[e];
    int dst = is64 ? ei[2 * (NEDGE + e)] : ei[NEDGE + e];
    int p = atomicAdd(&deg[dst], 1);
    csr[(size_t)dst * CAP + p] = src;
  } else {
    int idx = (b - 1632) * 256 + tid;
    float v = b_a1[idx & 127];
#pragma unroll 8
    for (int c = 0; c < 64; ++c) v += part[(size_t)c * (D_IN * D_EMB) + idx];
    xt[idx] = fmaxf(v, 0.f);
  }
}

// ---------------------------------------------------------------------------
// L3: xa GEMM -> bf16 [0,8) | GAT aggregation [8,3080)
// (xa first so its 8 blocks run concurrently with the GAT sea, not as a tail)
// ---------------------------------------------------------------------------
#define WCAP 192
__global__ __launch_bounds__(256) void l3_kernel(
    const int* __restrict__ deg, const int* __restrict__ csr,
    const float* __restrict__ sc_s, const float* __restrict__ sc_d,
    const float* __restrict__ g, const float* __restrict__ b_g,
    ushort* __restrict__ hhi, ushort* __restrict__ hlo,
    const float* __restrict__ xt, const float* __restrict__ Wa2,
    const float* __restrict__ b_a2,
    ushort* __restrict__ xahi, ushort* __restrict__ xalo)
{
  __shared__ float smem[4096];
  int b = blockIdx.x;
  int tid = threadIdx.x;
  if (b >= 8) {
    float (*wbuf)[WCAP] = (float(*)[WCAP])smem;
    int   (*sbuf)[WCAP] = (int(*)[WCAP])(smem + 4 * WCAP);
    int lane = tid & 63;
    int w = tid >> 6;
    int i = (b - 8) * 4 + w;
    int dg = deg[i];
    int base = i * CAP;
    float scd = sc_d[i];
    float mymax = -3.4e38f;
    for (int j = lane; j <= dg; j += 64) {
      int s = (j < dg) ? csr[base + j] : i;
      float e = sc_s[s] + scd;
      e = (e > 0.f) ? e : 0.2f * e;
      mymax = fmaxf(mymax, e);
      if (j < WCAP) sbuf[w][j] = s;
    }
#pragma unroll
    for (int off = 32; off; off >>= 1) mymax = fmaxf(mymax, __shfl_xor(mymax, off));
    float sum = 0.f;
    for (int j = lane; j <= dg; j += 64) {
      int s = (j < WCAP) ? sbuf[w][j] : ((j < dg) ? csr[base + j] : i);
      float e = sc_s[s] + scd;
      e = (e > 0.f) ? e : 0.2f * e;
      float ex = __expf(e - mymax);
      sum += ex;
      if (j < WCAP) wbuf[w][j] = ex;
    }
#pragma unroll
    for (int off = 32; off; off >>= 1) sum += __shfl_xor(sum, off);
    float inv = 1.f / sum;
    float acc = 0.f;   // lane == feature
    for (int j = 0; j <= dg; ++j) {
      int s; float ex;
      if (j < WCAP) { s = sbuf[w][j]; ex = wbuf[w][j]; }
      else {
        s = (j < dg) ? csr[base + j] : i;
        float e = sc_s[s] + scd;
        e = (e > 0.f) ? e : 0.2f * e;
        ex = __expf(e - mymax);
      }
      acc = fmaf(ex * inv, g[(size_t)s * 64 + lane], acc);
    }
    float val = acc + b_g[lane];
    size_t o = (size_t)i * 64 + lane;
    ushort hi = f2bf(val);
    hhi[o] = hi;
    hlo[o] = f2bf(val - bf2f(hi));
  } else {
    // xa = xt @ W_a2^T + b_a2 -> bf16 hi/lo
    float* As = smem;          // [32][64]
    float* Bs = smem + 2048;   // [32][64]
    int m0 = b * 64;
    int tx = tid & 15, ty = tid >> 4;
    float acc[4][4] = {};
    for (int k0 = 0; k0 < D_EMB; k0 += 32) {
#pragma unroll
      for (int p = 0; p < 2; ++p) {
        int idx = tid + p * 256;
        int row = idx >> 3;
        int kq = idx & 7;
        float4 va = *(const float4*)(xt + (size_t)(m0 + row) * D_EMB + k0 + kq * 4);
        As[(kq * 4 + 0) * 64 + row] = va.x; As[(kq * 4 + 1) * 64 + row] = va.y;
        As[(kq * 4 + 2) * 64 + row] = va.z; As[(kq * 4 + 3) * 64 + row] = va.w;
        float4 vb = *(const float4*)(Wa2 + (size_t)row * D_EMB + k0 + kq * 4);
        Bs[(kq * 4 + 0) * 64 + row] = vb.x; Bs[(kq * 4 + 1) * 64 + row] = vb.y;
        Bs[(kq * 4 + 2) * 64 + row] = vb.z; Bs[(kq * 4 + 3) * 64 + row] = vb.w;
      }
      __syncthreads();
#pragma unroll
      for (int k = 0; k < 32; ++k) {
        float a[4], bb[4];
        *(float4*)a = *(const float4*)&As[k * 64 + ty * 4];
        *(float4*)bb = *(const float4*)&Bs[k * 64 + tx * 4];
#pragma unroll
        for (int r = 0; r < 4; ++r)
#pragma unroll
          for (int c = 0; c < 4; ++c)
            acc[r][c] = fmaf(a[r], bb[c], acc[r][c]);
      }
      __syncthreads();
    }
#pragma unroll
    for (int r = 0; r < 4; ++r) {
      int m = m0 + ty * 4 + r;
      ushort4 h, l;
      ushort* ph = &h.x; ushort* pl = &l.x;
#pragma unroll
      for (int c = 0; c < 4; ++c) {
        float v = acc[r][c] + b_a2[tx * 4 + c];
        ushort hb = f2bf(v);
        ph[c] = hb;
        pl[c] = f2bf(v - bf2f(hb));
      }
      *(ushort4*)(xahi + (size_t)m * D_OUT + tx * 4) = h;
      *(ushort4*)(xalo + (size_t)m * D_OUT + tx * 4) = l;
    }
  }
}

// ---------------------------------------------------------------------------
// L4: out_x [0,384) | sigmoid(h h^T) [384,9600) — NT stores for both outputs
// ---------------------------------------------------------------------------
__global__ __launch_bounds__(256) void l4_kernel(
    const ushort* __restrict__ hhi, const ushort* __restrict__ hlo,
    const ushort* __restrict__ xahi, const ushort* __restrict__ xalo,
    float* __restrict__ out_x, float* __restrict__ out_s)
{
  int b = blockIdx.x;
  int lane = threadIdx.x & 63;
  int wv = threadIdx.x >> 6;
  if (b < 384) {
    int i0 = (b >> 2) * 128 + (wv >> 1) * 64;
    int j0 = (b & 3) * 128 + (wv & 1) * 64;
    mfma_tile64_f32out(lane, i0, j0, hhi, hlo, xahi, xalo,
                       out_x, D_OUT, D_OUT, D_OUT, D_IN);
    return;
  }
  int bb = b - 384;
  int iT = bb / 96;
  int jT = bb - iT * 96;
  int i0 = iT * 128 + (wv >> 1) * 64;
  int j0 = jT * 128 + (wv & 1) * 64;
  int lm = lane & 15, lk = lane >> 4;
  f32x4 acc[4][4];
#pragma unroll
  for (int r = 0; r < 4; ++r)
#pragma unroll
    for (int c = 0; c < 4; ++c) acc[r][c] = (f32x4){0.f, 0.f, 0.f, 0.f};
#pragma unroll
  for (int ks = 0; ks < 2; ++ks) {
    short8 Ah[4], Al[4], Bh[4], Bl[4];
#pragma unroll
    for (int t = 0; t < 4; ++t) {
      size_t ra = (size_t)(i0 + t * 16 + lm) * 64 + ks * 32 + lk * 8;
      size_t rb = (size_t)(j0 + t * 16 + lm) * 64 + ks * 32 + lk * 8;
      Ah[t] = *(const short8*)(hhi + ra);
      Al[t] = *(const short8*)(hlo + ra);
      Bh[t] = *(const short8*)(hhi + rb);
      Bl[t] = *(const short8*)(hlo + rb);
    }
#pragma unroll
    for (int r = 0; r < 4; ++r)
#pragma unroll
      for (int c = 0; c < 4; ++c) {
        acc[r][c] = __builtin_amdgcn_mfma_f32_16x16x32_bf16(Ah[r], Bh[c], acc[r][c], 0, 0, 0);
        acc[r][c] = __builtin_amdgcn_mfma_f32_16x16x32_bf16(Ah[r], Bl[c], acc[r][c], 0, 0, 0);
        acc[r][c] = __builtin_amdgcn_mfma_f32_16x16x32_bf16(Al[r], Bh[c], acc[r][c], 0, 0, 0);
      }
  }
#pragma unroll
  for (int r = 0; r < 4; ++r)
#pragma unroll
    for (int c = 0; c < 4; ++c) {
#pragma unroll
      for (int q = 0; q < 4; ++q) {
        float v = acc[r][c][q];
        float ex = __expf(-v);
#if __has_builtin(__builtin_amdgcn_rcpf)
        float s = __builtin_amdgcn_rcpf(1.f + ex);
#else
        float s = 1.f / (1.f + ex);
#endif
        __builtin_nontemporal_store(s,
            &out_s[(size_t)(i0 + r * 16 + lk * 4 + q) * N_NODES + (j0 + c * 16 + lm)]);
      }
    }
}

// ---------------------------------------------------------------------------
extern "C" void kernel_launch(void* const* d_in, const int* in_sizes, int n_in,
                              void* d_out, int out_size, void* d_ws, size_t ws_size,
                              hipStream_t stream)
{
  const float* x     = (const float*)d_in[0];
  const float* W_s1  = (const float*)d_in[1];
  const float* b_s1  = (const float*)d_in[2];
  const float* W_g   = (const float*)d_in[3];
  const float* a_src = (const float*)d_in[4];
  const float* a_dst = (const float*)d_in[5];
  const float* b_g   = (const float*)d_in[6];
  const float* W_a1  = (const float*)d_in[7];
  const float* b_a1  = (const float*)d_in[8];
  const float* W_a2  = (const float*)d_in[9];
  const float* b_a2  = (const float*)d_in[10];
  const int*   ei    = (const int*)d_in[11];

  // ---- workspace carve-up (~32 MB total)
  float* ws   = (float*)d_ws;
  float* g    = ws;                               // 786432
  float* sc_s = g + (size_t)N_NODES * D_OUT;      // 12288
  float* sc_d = sc_s + N_NODES;                   // 12288
  float* part = sc_d + N_NODES;                   // 64*65536 = 4194304
  float* xt   = part + (size_t)64 * D_IN * D_EMB; // 65536
  int* deg    = (int*)(xt + D_IN * D_EMB);        // 12288
  int* csr    = deg + N_NODES;                    // 12288*160 = 1966080
  ushort* up  = (ushort*)(csr + (size_t)N_NODES * CAP);
  ushort* Ws1hi = up;                        up += (size_t)D_EMB * D_IN;
  ushort* Ws1lo = up;                        up += (size_t)D_EMB * D_IN;
  ushort* Wghi  = up;                        up += (size_t)D_OUT * D_EMB;
  ushort* Wglo  = up;                        up += (size_t)D_OUT * D_EMB;
  ushort* hhi   = up;                        up += (size_t)N_NODES * D_OUT;
  ushort* hlo   = up;                        up += (size_t)N_NODES * D_OUT;
  ushort* xahi  = up;                        up += (size_t)D_IN * D_OUT;
  ushort* xalo  = up;                        up += (size_t)D_IN * D_OUT;
  (void)ws_size; (void)in_sizes; (void)n_in; (void)out_size;

  float* out_x = (float*)d_out;                       // 12288*512
  float* out_s = out_x + (size_t)N_NODES * D_IN;      // 12288*12288

  // L1: xt_splitk || conv W || zero deg            (632 blocks)
  prep_kernel<<<632, 256, 0, stream>>>(x, W_s1, W_g, W_a1,
      Ws1hi, Ws1lo, Wghi, Wglo, deg, part);
  // L2: fused x1+g+scores || padded-CSR scatter || xt_ep   (1888 blocks)
  l2_kernel<<<1888, 256, 0, stream>>>(ei, deg, csr, x, Ws1hi, Ws1lo, b_s1,
      Wghi, Wglo, g, a_src, a_dst, sc_s, sc_d, part, b_a1, xt);
  // L3: xa GEMM || GAT                             (3080 blocks)
  l3_kernel<<<3080, 256, 0, stream>>>(deg, csr, sc_s, sc_d, g, b_g,
      hhi, hlo, xt, W_a2, b_a2, xahi, xalo);
  // L4: out_x || sigmoid(h h^T)                    (9600 blocks)
  l4_kernel<<<9600, 256, 0, stream>>>(hhi, hlo, xahi, xalo, out_x, out_s);
}